// Round 9
// baseline (237.518 us; speedup 1.0000x reference)
//
#include <hip/hip_runtime.h>
#include <hip/hip_bf16.h>
#include <math.h>

// ---------------------------------------------------------------------------
// GIN 2-layer forward. CSR via two-level counting sort (single edge-list read,
// packed 26-bit pairs, byte-offset col[]), bf16 gathers (f32 sums), bf16 MFMA
// GEMMs with fused MLP (gemm1+gemm2 via LDS mid-tile), aggregate-after-
// projection for conv2 ((h+Ah)@W1b == m + Am, m=h@W1b), and a fused
// gather+GEMM+log_softmax final stage.
// N=100000, E=1200000, IN=64, HID=128, OUT=40.
// ---------------------------------------------------------------------------

#define WS_ALIGN 256
#define NBLK_C 256          // edge-chunk blocks for bucket sort
#define NPB_SHIFT 9         // 512 nodes per coarse bucket
#define NPB 512
#define SCAN_T 256
#define SCAN_E 1024         // elements per scan block

typedef __attribute__((ext_vector_type(8))) __bf16 bf16x8;
typedef __attribute__((ext_vector_type(4))) float f32x4;

__device__ inline unsigned short f2b(float f) {      // RNE f32->bf16
  unsigned int x = __float_as_uint(f);
  return (unsigned short)((x + 0x7fffu + ((x >> 16) & 1u)) >> 16);
}
__device__ inline float b2f(unsigned short u) {
  return __uint_as_float(((unsigned int)u) << 16);
}

// --- dtype sniff: edge_index may be int64 (ref) or int32 (x64-disabled JAX).
__global__ __launch_bounds__(256) void sniff_kernel(const unsigned int* __restrict__ ew,
                                                    unsigned int* __restrict__ flag, int E) {
  unsigned int acc = 0;
  int i = threadIdx.x;
  for (int j = 0; j < 16; ++j) {
    long long s = ((long long)(i * 16 + j) * 292 + 7) % E;
    acc |= ew[2 * (size_t)s + 1];
  }
  if (acc) atomicOr(flag, 1u);   // nonzero -> int32 layout
}

// --- K1: single edge-list pass: coarse histogram + compacted pairs.
// pairs_u[e] = (src<<9)|(dst&511), bucket8[e] = dst>>9.
__global__ __launch_bounds__(256) void ehist_kernel(
    const unsigned int* __restrict__ ew, const unsigned int* __restrict__ flag,
    int* __restrict__ gcount, unsigned int* __restrict__ pairs_u,
    unsigned char* __restrict__ bucket8, int E, int NB) {
  extern __shared__ int hist[];
  const bool is64 = (*flag == 0u);
  const int t = threadIdx.x, blk = blockIdx.x;
  for (int i = t; i < NB; i += 256) hist[i] = 0;
  __syncthreads();
  const int chunk = (E + NBLK_C - 1) / NBLK_C;
  const int beg = blk * chunk, end = min(E, beg + chunk);
  for (int e = beg + t; e < end; e += 256) {
    unsigned int s, d;
    if (is64) { s = ew[2 * (size_t)e]; d = ew[2 * (size_t)(E + e)]; }
    else      { s = ew[(size_t)e];     d = ew[(size_t)E + e]; }
    atomicAdd(&hist[d >> NPB_SHIFT], 1);
    pairs_u[e] = (s << NPB_SHIFT) | (d & (NPB - 1));
    bucket8[e] = (unsigned char)(d >> NPB_SHIFT);
  }
  __syncthreads();
  for (int i = t; i < NB; i += 256) gcount[i * NBLK_C + blk] = hist[i];
}

// --- K2: 3-pass parallel exclusive scan of gcount[tot] in place.
__global__ __launch_bounds__(SCAN_T) void pscan1_kernel(const int* __restrict__ g,
                                                        int* __restrict__ bsum, int tot) {
  __shared__ int s[SCAN_T];
  int b = blockIdx.x, t = threadIdx.x;
  int base = b * SCAN_E + t * 4;
  int v = 0;
#pragma unroll
  for (int k = 0; k < 4; ++k) { int i = base + k; if (i < tot) v += g[i]; }
  s[t] = v; __syncthreads();
  for (int off = SCAN_T / 2; off >= 1; off >>= 1) {
    if (t < off) s[t] += s[t + off];
    __syncthreads();
  }
  if (t == 0) bsum[b] = s[0];
}

__global__ void pscan2_kernel(int* __restrict__ bsum, int nb) {
  if (blockIdx.x == 0 && threadIdx.x == 0) {
    int run = 0;
    for (int i = 0; i < nb; ++i) { int v = bsum[i]; bsum[i] = run; run += v; }
    bsum[nb] = run;
  }
}

__global__ __launch_bounds__(SCAN_T) void pscan3_kernel(
    int* __restrict__ g, const int* __restrict__ bsum, int tot) {
  __shared__ int s[SCAN_T];
  int b = blockIdx.x, t = threadIdx.x;
  int base = b * SCAN_E + t * 4;
  int d[4]; int v = 0;
#pragma unroll
  for (int k = 0; k < 4; ++k) { int i = base + k; d[k] = (i < tot) ? g[i] : 0; v += d[k]; }
  s[t] = v; __syncthreads();
  for (int off = 1; off < SCAN_T; off <<= 1) {
    int u = (t >= off) ? s[t - off] : 0;
    __syncthreads();
    s[t] += u;
    __syncthreads();
  }
  int exc = s[t] - v + bsum[b];
#pragma unroll
  for (int k = 0; k < 4; ++k) {
    int i = base + k;
    if (i < tot) { g[i] = exc; exc += d[k]; }
  }
}

// --- K3: scatter packed pairs bucket-major using LDS cursors.
__global__ __launch_bounds__(256) void bscatter2_kernel(
    const unsigned int* __restrict__ pairs_u, const unsigned char* __restrict__ bucket8,
    const int* __restrict__ gscan, unsigned int* __restrict__ pairs_s, int E, int NB) {
  extern __shared__ int cur[];
  const int t = threadIdx.x, blk = blockIdx.x;
  for (int i = t; i < NB; i += 256) cur[i] = gscan[i * NBLK_C + blk];
  __syncthreads();
  const int chunk = (E + NBLK_C - 1) / NBLK_C;
  const int beg = blk * chunk, end = min(E, beg + chunk);
  for (int e = beg + t; e < end; e += 256) {
    int b = bucket8[e];
    int pos = atomicAdd(&cur[b], 1);
    pairs_s[pos] = pairs_u[e];
  }
}

// --- K4: per-bucket LDS counting sort -> rowptr + dense col writes.
// col[] holds BYTE offsets (src*128) into bf16 [N,64] feature arrays.
__global__ __launch_bounds__(256) void bsort_kernel(
    const unsigned int* __restrict__ pairs, const int* __restrict__ gscan,
    int* __restrict__ rowptr, int* __restrict__ col, int E, int N, int NB) {
  __shared__ int cnt[NPB];
  __shared__ int scn[NPB];
  __shared__ int cur[NPB];
  __shared__ int part[256];
  const int t = threadIdx.x, b = blockIdx.x;
  const int base = gscan[(size_t)b * NBLK_C];
  const int bend = (b + 1 < NB) ? gscan[(size_t)(b + 1) * NBLK_C] : E;
  const int n0 = b << NPB_SHIFT;

  cnt[2 * t] = 0; cnt[2 * t + 1] = 0;
  __syncthreads();
  for (int j = base + t; j < bend; j += 256)
    atomicAdd(&cnt[pairs[j] & (NPB - 1)], 1);
  __syncthreads();

  int c0 = cnt[2 * t], c1 = cnt[2 * t + 1];
  part[t] = c0 + c1;
  __syncthreads();
  for (int off = 1; off < 256; off <<= 1) {
    int u = (t >= off) ? part[t - off] : 0;
    __syncthreads();
    part[t] += u;
    __syncthreads();
  }
  int exc = part[t] - (c0 + c1);
  scn[2 * t] = exc; scn[2 * t + 1] = exc + c0;
  cur[2 * t] = base + exc; cur[2 * t + 1] = base + exc + c0;

  int g0 = n0 + 2 * t, g1 = n0 + 2 * t + 1;
  if (g0 < N) rowptr[g0] = base + scn[2 * t];
  if (g1 < N) rowptr[g1] = base + scn[2 * t + 1];
  if (b == NB - 1 && t == 0) rowptr[N] = E;
  __syncthreads();

  for (int j = base + t; j < bend; j += 256) {
    unsigned int p = pairs[j];
    int pos = atomicAdd(&cur[p & (NPB - 1)], 1);
    col[pos] = (int)((p >> NPB_SHIFT) << 7);   // byte offset
  }
}

// --- cast x (f32) -> xb (bf16), vectorized
__global__ __launch_bounds__(256) void castx_kernel(
    const float4* __restrict__ X, ushort4* __restrict__ XB, int tot4) {
  int i = blockIdx.x * 256 + threadIdx.x;
  if (i >= tot4) return;
  float4 v = X[i];
  ushort4 r;
  r.x = f2b(v.x); r.y = f2b(v.y); r.z = f2b(v.z); r.w = f2b(v.w);
  XB[i] = r;
}

// --- weight transpose + cast: Wt[fo][k] = bf16(W[k][fo]); zero-pad fo>=Fo, k>=Fi
__global__ __launch_bounds__(256) void transw_kernel(
    const float* __restrict__ W, unsigned short* __restrict__ Wt,
    int Fi, int FiPad, int Fo, int FoPad) {
  int i = blockIdx.x * 256 + threadIdx.x;
  if (i >= FoPad * FiPad) return;
  int fo = i / FiPad, k = i - fo * FiPad;
  float v = (fo < Fo && k < Fi) ? W[(size_t)k * Fo + fo] : 0.f;
  Wt[i] = f2b(v);
}

// --- gather over bf16 [N,64] rows: out[n] = bf16(X[n] + sum X[col[j]])
// One wave per node, lane = feature, col[] holds byte offsets.
__global__ __launch_bounds__(256) void gatherB_kernel(
    const unsigned short* __restrict__ X, const int* __restrict__ rowptr,
    const int* __restrict__ colb, unsigned short* __restrict__ out, int N) {
  const int lane = threadIdx.x & 63;
  const int n = blockIdx.x * 4 + (threadIdx.x >> 6);
  if (n >= N) return;
  const char* Xc = (const char*)X;
  const int l2 = lane * 2;
  const int beg = rowptr[n], end = rowptr[n + 1];
  float a0 = b2f(*(const unsigned short*)(Xc + ((size_t)n << 7) + l2));
  float a1 = 0.f, a2 = 0.f, a3 = 0.f;
  int j = beg;
  for (; j + 4 <= end; j += 4) {
    int c0 = colb[j], c1 = colb[j + 1], c2 = colb[j + 2], c3 = colb[j + 3];
    a0 += b2f(*(const unsigned short*)(Xc + c0 + l2));
    a1 += b2f(*(const unsigned short*)(Xc + c1 + l2));
    a2 += b2f(*(const unsigned short*)(Xc + c2 + l2));
    a3 += b2f(*(const unsigned short*)(Xc + c3 + l2));
  }
  for (; j < end; ++j) a0 += b2f(*(const unsigned short*)(Xc + colb[j] + l2));
  out[(size_t)n * 64 + lane] = f2b(a0 + a1 + a2 + a3);
}

// --- fused MLP: h = relu(relu(xa@W1+b1)@W2+b2). mid lives in a swizzled LDS
// tile [64][128]. Block: 4 waves x 16 nodes. 64 KB LDS.
__global__ __launch_bounds__(256) void gemm12_kernel(
    const unsigned short* __restrict__ A, const unsigned short* __restrict__ W1G,
    const unsigned short* __restrict__ W2G, const float* __restrict__ b1,
    const float* __restrict__ b2, unsigned short* __restrict__ out, int N) {
  __shared__ unsigned short W1l[128 * 64];    // 16 KB
  __shared__ unsigned short W2l[128 * 128];   // 32 KB
  __shared__ unsigned short Ml[64 * 128];     // 16 KB
  const int t = threadIdx.x;
  const int n0 = blockIdx.x * 64;

  for (int c = t; c < 128 * 64 / 8; c += 256) {      // W1: CPR=8
    int row = c >> 3;
    uint4 v = ((const uint4*)W1G)[c];
    int boff = (c * 16) ^ ((row & 7) << 4);
    *(uint4*)((char*)W1l + boff) = v;
  }
  for (int c = t; c < 128 * 128 / 8; c += 256) {     // W2: CPR=16
    int row = c >> 4;
    uint4 v = ((const uint4*)W2G)[c];
    int boff = (c * 16) ^ ((row & 7) << 4);
    *(uint4*)((char*)W2l + boff) = v;
  }
  __syncthreads();

  const int l = t & 63, w = t >> 6;
  const int kgrp = l >> 4, rc = l & 15;
  int arow = n0 + w * 16 + rc;
  int arowc = arow < N ? arow : N - 1;

  f32x4 acc[8];
#pragma unroll
  for (int nf = 0; nf < 8; ++nf) acc[nf] = (f32x4){0.f, 0.f, 0.f, 0.f};

#pragma unroll
  for (int k0 = 0; k0 < 64; k0 += 32) {
    bf16x8 a = *(const bf16x8*)(A + (size_t)arowc * 64 + k0 + kgrp * 8);
#pragma unroll
    for (int nf = 0; nf < 8; ++nf) {
      int frow = nf * 16 + rc;
      int boff = ((frow * 64 + k0 + kgrp * 8) * 2) ^ ((frow & 7) << 4);
      bf16x8 b = *(const bf16x8*)((const char*)W1l + boff);
      acc[nf] = __builtin_amdgcn_mfma_f32_16x16x32_bf16(a, b, acc[nf], 0, 0, 0);
    }
  }
  // bias1 + relu -> Ml (swizzled [64][128] bf16)
#pragma unroll
  for (int nf = 0; nf < 8; ++nf) {
    int colv = nf * 16 + rc;
    float bs = b1[colv];
    int chunk = colv >> 3;
    int inb = (rc & 7) * 2;
#pragma unroll
    for (int q = 0; q < 4; ++q) {
      int row = w * 16 + kgrp * 4 + q;
      float v = fmaxf(acc[nf][q] + bs, 0.f);
      int boff = row * 256 + ((chunk * 16) ^ ((row & 7) << 4)) + inb;
      *(unsigned short*)((char*)Ml + boff) = f2b(v);
    }
  }
  __syncthreads();

#pragma unroll
  for (int nf = 0; nf < 8; ++nf) acc[nf] = (f32x4){0.f, 0.f, 0.f, 0.f};
  const int arow2 = w * 16 + rc;
#pragma unroll
  for (int k0 = 0; k0 < 128; k0 += 32) {
    int chunk = (k0 >> 3) + kgrp;
    int aoff = arow2 * 256 + ((chunk * 16) ^ ((arow2 & 7) << 4));
    bf16x8 a = *(const bf16x8*)((const char*)Ml + aoff);
#pragma unroll
    for (int nf = 0; nf < 8; ++nf) {
      int frow = nf * 16 + rc;
      int boff = ((frow * 128 + k0 + kgrp * 8) * 2) ^ ((frow & 7) << 4);
      bf16x8 b = *(const bf16x8*)((const char*)W2l + boff);
      acc[nf] = __builtin_amdgcn_mfma_f32_16x16x32_bf16(a, b, acc[nf], 0, 0, 0);
    }
  }
#pragma unroll
  for (int nf = 0; nf < 8; ++nf) {
    int fo = nf * 16 + rc;
    float bs = b2[fo];
#pragma unroll
    for (int q = 0; q < 4; ++q) {
      int n = n0 + w * 16 + kgrp * 4 + q;
      if (n < N) {
        float v = fmaxf(acc[nf][q] + bs, 0.f);
        out[(size_t)n * 128 + fo] = f2b(v);
      }
    }
  }
}

// --- bf16 MFMA GEMM for m = h@W1b: out[n][0..FoPad) = A[n]@W (no bias/act).
// NOTE: writes ALL FoPad columns with stride FoPad — cols >= Fo are zeros
// (Wt zero-padded). Downstream readers treat m as [N, FoPad].
template<int Fi, int FoPad>
__global__ __launch_bounds__(256) void gemm_mfma(
    const unsigned short* __restrict__ A, const unsigned short* __restrict__ WtG,
    unsigned short* __restrict__ out, int N) {
  __shared__ unsigned short Wlds[FoPad * Fi];
  const int t = threadIdx.x;
  const int n0 = blockIdx.x * 64;

  constexpr int NCH = FoPad * Fi / 8;
  constexpr int CPR = Fi / 8;
  for (int c = t; c < NCH; c += 256) {
    int row = c / CPR;
    uint4 v = ((const uint4*)WtG)[c];
    int boff = (c * 16) ^ ((row & 7) << 4);
    *(uint4*)((char*)Wlds + boff) = v;
  }
  __syncthreads();

  const int l = t & 63, w = t >> 6;
  const int kgrp = l >> 4, rc = l & 15;
  int arow = n0 + w * 16 + rc;
  int arowc = arow < N ? arow : N - 1;

  constexpr int NF = FoPad / 16;
  f32x4 acc[NF];
#pragma unroll
  for (int nf = 0; nf < NF; ++nf) acc[nf] = (f32x4){0.f, 0.f, 0.f, 0.f};

#pragma unroll
  for (int k0 = 0; k0 < Fi; k0 += 32) {
    bf16x8 a = *(const bf16x8*)(A + (size_t)arowc * Fi + k0 + kgrp * 8);
#pragma unroll
    for (int nf = 0; nf < NF; ++nf) {
      int frow = nf * 16 + rc;
      int boff = ((frow * Fi + k0 + kgrp * 8) * 2) ^ ((frow & 7) << 4);
      bf16x8 b = *(const bf16x8*)((const char*)Wlds + boff);
      acc[nf] = __builtin_amdgcn_mfma_f32_16x16x32_bf16(a, b, acc[nf], 0, 0, 0);
    }
  }

#pragma unroll
  for (int nf = 0; nf < NF; ++nf) {
    int fo = nf * 16 + rc;
#pragma unroll
    for (int q = 0; q < 4; ++q) {
      int n = n0 + w * 16 + kgrp * 4 + q;
      if (n < N) out[(size_t)n * FoPad + fo] = f2b(acc[nf][q]);
    }
  }
}

// --- fused final: per 64-node block, gather v=relu(m + Am + b1b) into a
// swizzled LDS tile, then z = v@W2b + b2b (MFMA, FoPad=48) + log_softmax.
__global__ __launch_bounds__(256) void gather_sm_kernel(
    const unsigned short* __restrict__ M, const int* __restrict__ rowptr,
    const int* __restrict__ colb, const float* __restrict__ b1,
    const unsigned short* __restrict__ W4G, const float* __restrict__ b2,
    float* __restrict__ out, int N) {
  __shared__ unsigned short Vl[64 * 64];    // 8 KB
  __shared__ unsigned short W4l[48 * 64];   // 6 KB
  __shared__ float bl[48];
  const int t = threadIdx.x;
  const int n0 = blockIdx.x * 64;

  for (int c = t; c < 48 * 64 / 8; c += 256) {   // CPR=8
    int row = c >> 3;
    uint4 v = ((const uint4*)W4G)[c];
    int boff = (c * 16) ^ ((row & 7) << 4);
    *(uint4*)((char*)W4l + boff) = v;
  }
  if (t < 48) bl[t] = (t < 40) ? b2[t] : 0.f;

  const int l = t & 63, w = t >> 6;
  const int l2 = l * 2;
  const char* Mc = (const char*)M;
  const float bb = (l < 40) ? b1[l] : 0.f;

  // phase A: each wave gathers 16 node rows
  for (int i = 0; i < 16; ++i) {
    const int row = w * 16 + i;
    const int n = n0 + row;
    float r = 0.f;
    if (n < N) {
      const int beg = rowptr[n], end = rowptr[n + 1];
      float a0 = b2f(*(const unsigned short*)(Mc + ((size_t)n << 7) + l2));
      float a1 = 0.f, a2 = 0.f, a3 = 0.f;
      int j = beg;
      for (; j + 4 <= end; j += 4) {
        int c0 = colb[j], c1 = colb[j + 1], c2 = colb[j + 2], c3 = colb[j + 3];
        a0 += b2f(*(const unsigned short*)(Mc + c0 + l2));
        a1 += b2f(*(const unsigned short*)(Mc + c1 + l2));
        a2 += b2f(*(const unsigned short*)(Mc + c2 + l2));
        a3 += b2f(*(const unsigned short*)(Mc + c3 + l2));
      }
      for (; j < end; ++j) a0 += b2f(*(const unsigned short*)(Mc + colb[j] + l2));
      r = fmaxf(a0 + a1 + a2 + a3 + bb, 0.f);
      if (l >= 40) r = 0.f;   // padded features: force exact zero
    }
    int chunk = l >> 3;
    int boff = row * 128 + ((chunk * 16) ^ ((row & 7) << 4)) + (l & 7) * 2;
    *(unsigned short*)((char*)Vl + boff) = f2b(r);
  }
  __syncthreads();

  // phase B: z = V@W4 + b2, log_softmax, write f32 out
  const int kgrp = l >> 4, rc = l & 15;
  const int arow = w * 16 + rc;
  f32x4 acc[3];
#pragma unroll
  for (int nf = 0; nf < 3; ++nf) acc[nf] = (f32x4){0.f, 0.f, 0.f, 0.f};
#pragma unroll
  for (int k0 = 0; k0 < 64; k0 += 32) {
    int chunk = (k0 >> 3) + kgrp;
    int aoff = arow * 128 + ((chunk * 16) ^ ((arow & 7) << 4));
    bf16x8 a = *(const bf16x8*)((const char*)Vl + aoff);
#pragma unroll
    for (int nf = 0; nf < 3; ++nf) {
      int frow = nf * 16 + rc;
      int boff = ((frow * 64 + k0 + kgrp * 8) * 2) ^ ((frow & 7) << 4);
      bf16x8 b = *(const bf16x8*)((const char*)W4l + boff);
      acc[nf] = __builtin_amdgcn_mfma_f32_16x16x32_bf16(a, b, acc[nf], 0, 0, 0);
    }
  }

  const bool v2 = (rc < 8);
  float bs0 = bl[rc], bs1 = bl[16 + rc], bs2 = bl[32 + rc];
#pragma unroll
  for (int q = 0; q < 4; ++q) {
    float z0 = acc[0][q] + bs0;
    float z1 = acc[1][q] + bs1;
    float z2 = acc[2][q] + bs2;
    float m = fmaxf(z0, z1);
    if (v2) m = fmaxf(m, z2);
#pragma unroll
    for (int o = 8; o >= 1; o >>= 1) m = fmaxf(m, __shfl_xor(m, o, 64));
    float s = expf(z0 - m) + expf(z1 - m) + (v2 ? expf(z2 - m) : 0.f);
#pragma unroll
    for (int o = 8; o >= 1; o >>= 1) s += __shfl_xor(s, o, 64);
    float ls = m + logf(s);
    int n = n0 + w * 16 + kgrp * 4 + q;
    if (n < N) {
      float* op = out + (size_t)n * 40;
      op[rc] = z0 - ls;
      op[16 + rc] = z1 - ls;
      if (v2) op[32 + rc] = z2 - ls;
    }
  }
}

extern "C" void kernel_launch(void* const* d_in, const int* in_sizes, int n_in,
                              void* d_out, int out_size, void* d_ws, size_t ws_size,
                              hipStream_t stream) {
  const float*        x   = (const float*)d_in[0];
  const unsigned int* ew  = (const unsigned int*)d_in[1];
  const float*        W1a = (const float*)d_in[2];
  const float*        b1a = (const float*)d_in[3];
  const float*        W2a = (const float*)d_in[4];
  const float*        b2a = (const float*)d_in[5];
  const float*        W1b = (const float*)d_in[6];
  const float*        b1b = (const float*)d_in[7];
  const float*        W2b = (const float*)d_in[8];
  const float*        b2b = (const float*)d_in[9];

  const int N = in_sizes[0] / 64;     // 100000
  const int E = in_sizes[1] / 2;      // 1200000
  const int NB = (N + NPB - 1) >> NPB_SHIFT;   // coarse buckets (196)
  float* out = (float*)d_out;

  char* ws = (char*)d_ws;
  size_t off = 0;
  auto alloc = [&](size_t bytes) {
    char* p = ws + off;
    off += (bytes + WS_ALIGN - 1) & ~(size_t)(WS_ALIGN - 1);
    return p;
  };
  unsigned int*  flag   = (unsigned int*)alloc(4);
  int*           rowptr = (int*)alloc((size_t)(N + 2) * 4);
  int*           gscan  = (int*)alloc((size_t)NB * NBLK_C * 4);
  int*           bsum2  = (int*)alloc(256 * 4);
  int*           col    = (int*)alloc((size_t)E * 4);       // byte offsets
  unsigned short* Wt1   = (unsigned short*)alloc((size_t)128 * 64 * 2);
  unsigned short* Wt2   = (unsigned short*)alloc((size_t)128 * 128 * 2);
  unsigned short* Wt3   = (unsigned short*)alloc((size_t)64 * 128 * 2);
  unsigned short* Wt4   = (unsigned short*)alloc((size_t)48 * 64 * 2);
  unsigned short* xb    = (unsigned short*)alloc((size_t)N * 64 * 2);   // bf16 x
  unsigned short* xa    = (unsigned short*)alloc((size_t)N * 64 * 2);   // x+Ax
  unsigned short* h     = (unsigned short*)alloc((size_t)N * 128 * 2);  // 25.6 MB
  unsigned short* m     = (unsigned short*)alloc((size_t)N * 64 * 2);   // h@W1b
  // CSR-build staging aliases (lifetimes end before h/m are written):
  unsigned int*  pairs_u = (unsigned int*)h;                 // 4.8 MB
  unsigned char* bucket8 = (unsigned char*)(h + (size_t)N * 64);  // 1.2 MB
  unsigned int*  pairs_s = (unsigned int*)m;                 // 4.8 MB

  hipMemsetAsync(flag, 0, 4, stream);
  sniff_kernel<<<1, 256, 0, stream>>>(ew, flag, E);

  // --- CSR build
  const size_t ldsNB = (size_t)NB * 4;
  const int tot = NB * NBLK_C;
  const int nb2 = (tot + SCAN_E - 1) / SCAN_E;
  ehist_kernel<<<NBLK_C, 256, ldsNB, stream>>>(ew, flag, gscan, pairs_u, bucket8, E, NB);
  pscan1_kernel<<<nb2, SCAN_T, 0, stream>>>(gscan, bsum2, tot);
  pscan2_kernel<<<1, 64, 0, stream>>>(bsum2, nb2);
  pscan3_kernel<<<nb2, SCAN_T, 0, stream>>>(gscan, bsum2, tot);
  bscatter2_kernel<<<NBLK_C, 256, ldsNB, stream>>>(pairs_u, bucket8, gscan, pairs_s, E, NB);
  bsort_kernel<<<NB, 256, 0, stream>>>(pairs_s, gscan, rowptr, col, E, N, NB);

  // casts / weight transposes (bf16)
  castx_kernel<<<(N * 16 + 255) / 256, 256, 0, stream>>>((const float4*)x, (ushort4*)xb, N * 16);
  transw_kernel<<<(128 * 64 + 255) / 256, 256, 0, stream>>>(W1a, Wt1, 64, 64, 128, 128);
  transw_kernel<<<(128 * 128 + 255) / 256, 256, 0, stream>>>(W2a, Wt2, 128, 128, 128, 128);
  transw_kernel<<<(64 * 128 + 255) / 256, 256, 0, stream>>>(W1b, Wt3, 128, 128, 40, 64);
  transw_kernel<<<(48 * 64 + 255) / 256, 256, 0, stream>>>(W2b, Wt4, 40, 64, 40, 48);

  const int gGather = (N + 3) / 4;
  const int gGemm = (N + 63) / 64;

  // conv1: xa = x + A x ; h = relu(relu(xa@W1a+b1a)@W2a+b2a)  (fused MLP)
  gatherB_kernel<<<gGather, 256, 0, stream>>>(xb, rowptr, col, xa, N);
  gemm12_kernel<<<gGemm, 256, 0, stream>>>(xa, Wt1, Wt2, b1a, b2a, h, N);

  // conv2: m = h@W1b (padded [N,64], cols 40.. zero)
  gemm_mfma<128, 64><<<gGemm, 256, 0, stream>>>(h, Wt3, m, N);
  // out = lsm(relu(m + Am + b1b)@W2b + b2b)  (fused gather+GEMM+softmax)
  gather_sm_kernel<<<gGemm, 256, 0, stream>>>(m, rowptr, col, b1b, Wt4, b2b, out, N);
}

// Round 10
// 203.901 us; speedup vs baseline: 1.1649x; 1.1649x over previous
//
#include <hip/hip_runtime.h>
#include <hip/hip_bf16.h>
#include <math.h>

// ---------------------------------------------------------------------------
// GIN 2-layer forward. CSR via two-level counting sort (single edge-list read,
// packed 26-bit pairs, byte-offset col[]), bf16 gathers (f32 sums, 8-wide
// unroll), fused 3-stage MFMA MLP (xa -> mid -> h -> m, all tiles in LDS; the
// h activation never touches global memory), aggregate-after-projection for
// conv2 ((h+Ah)@W1b == m + Am, m=h@W1b), fused gather+GEMM+log_softmax final.
// N=100000, E=1200000, IN=64, HID=128, OUT=40.
// ---------------------------------------------------------------------------

#define WS_ALIGN 256
#define NBLK_C 256          // edge-chunk blocks for bucket sort
#define NPB_SHIFT 9         // 512 nodes per coarse bucket
#define NPB 512
#define SCAN_T 256
#define SCAN_E 1024         // elements per scan block

typedef __attribute__((ext_vector_type(8))) __bf16 bf16x8;
typedef __attribute__((ext_vector_type(4))) float f32x4;

__device__ inline unsigned short f2b(float f) {      // RNE f32->bf16
  unsigned int x = __float_as_uint(f);
  return (unsigned short)((x + 0x7fffu + ((x >> 16) & 1u)) >> 16);
}
__device__ inline float b2f(unsigned short u) {
  return __uint_as_float(((unsigned int)u) << 16);
}

// --- dtype sniff: edge_index may be int64 (ref) or int32 (x64-disabled JAX).
__global__ __launch_bounds__(256) void sniff_kernel(const unsigned int* __restrict__ ew,
                                                    unsigned int* __restrict__ flag, int E) {
  unsigned int acc = 0;
  int i = threadIdx.x;
  for (int j = 0; j < 16; ++j) {
    long long s = ((long long)(i * 16 + j) * 292 + 7) % E;
    acc |= ew[2 * (size_t)s + 1];
  }
  if (acc) atomicOr(flag, 1u);   // nonzero -> int32 layout
}

// --- K1: single edge-list pass: coarse histogram + compacted pairs.
__global__ __launch_bounds__(256) void ehist_kernel(
    const unsigned int* __restrict__ ew, const unsigned int* __restrict__ flag,
    int* __restrict__ gcount, unsigned int* __restrict__ pairs_u,
    unsigned char* __restrict__ bucket8, int E, int NB) {
  extern __shared__ int hist[];
  const bool is64 = (*flag == 0u);
  const int t = threadIdx.x, blk = blockIdx.x;
  for (int i = t; i < NB; i += 256) hist[i] = 0;
  __syncthreads();
  const int chunk = (E + NBLK_C - 1) / NBLK_C;
  const int beg = blk * chunk, end = min(E, beg + chunk);
  for (int e = beg + t; e < end; e += 256) {
    unsigned int s, d;
    if (is64) { s = ew[2 * (size_t)e]; d = ew[2 * (size_t)(E + e)]; }
    else      { s = ew[(size_t)e];     d = ew[(size_t)E + e]; }
    atomicAdd(&hist[d >> NPB_SHIFT], 1);
    pairs_u[e] = (s << NPB_SHIFT) | (d & (NPB - 1));
    bucket8[e] = (unsigned char)(d >> NPB_SHIFT);
  }
  __syncthreads();
  for (int i = t; i < NB; i += 256) gcount[i * NBLK_C + blk] = hist[i];
}

// --- K2: 3-pass parallel exclusive scan of gcount[tot] in place.
__global__ __launch_bounds__(SCAN_T) void pscan1_kernel(const int* __restrict__ g,
                                                        int* __restrict__ bsum, int tot) {
  __shared__ int s[SCAN_T];
  int b = blockIdx.x, t = threadIdx.x;
  int base = b * SCAN_E + t * 4;
  int v = 0;
#pragma unroll
  for (int k = 0; k < 4; ++k) { int i = base + k; if (i < tot) v += g[i]; }
  s[t] = v; __syncthreads();
  for (int off = SCAN_T / 2; off >= 1; off >>= 1) {
    if (t < off) s[t] += s[t + off];
    __syncthreads();
  }
  if (t == 0) bsum[b] = s[0];
}

__global__ void pscan2_kernel(int* __restrict__ bsum, int nb) {
  if (blockIdx.x == 0 && threadIdx.x == 0) {
    int run = 0;
    for (int i = 0; i < nb; ++i) { int v = bsum[i]; bsum[i] = run; run += v; }
    bsum[nb] = run;
  }
}

__global__ __launch_bounds__(SCAN_T) void pscan3_kernel(
    int* __restrict__ g, const int* __restrict__ bsum, int tot) {
  __shared__ int s[SCAN_T];
  int b = blockIdx.x, t = threadIdx.x;
  int base = b * SCAN_E + t * 4;
  int d[4]; int v = 0;
#pragma unroll
  for (int k = 0; k < 4; ++k) { int i = base + k; d[k] = (i < tot) ? g[i] : 0; v += d[k]; }
  s[t] = v; __syncthreads();
  for (int off = 1; off < SCAN_T; off <<= 1) {
    int u = (t >= off) ? s[t - off] : 0;
    __syncthreads();
    s[t] += u;
    __syncthreads();
  }
  int exc = s[t] - v + bsum[b];
#pragma unroll
  for (int k = 0; k < 4; ++k) {
    int i = base + k;
    if (i < tot) { g[i] = exc; exc += d[k]; }
  }
}

// --- K3: scatter packed pairs bucket-major using LDS cursors.
__global__ __launch_bounds__(256) void bscatter2_kernel(
    const unsigned int* __restrict__ pairs_u, const unsigned char* __restrict__ bucket8,
    const int* __restrict__ gscan, unsigned int* __restrict__ pairs_s, int E, int NB) {
  extern __shared__ int cur[];
  const int t = threadIdx.x, blk = blockIdx.x;
  for (int i = t; i < NB; i += 256) cur[i] = gscan[i * NBLK_C + blk];
  __syncthreads();
  const int chunk = (E + NBLK_C - 1) / NBLK_C;
  const int beg = blk * chunk, end = min(E, beg + chunk);
  for (int e = beg + t; e < end; e += 256) {
    int b = bucket8[e];
    int pos = atomicAdd(&cur[b], 1);
    pairs_s[pos] = pairs_u[e];
  }
}

// --- K4: per-bucket LDS counting sort -> rowptr + dense col writes.
// col[] holds BYTE offsets (src*128) into bf16 [N,64] feature arrays.
__global__ __launch_bounds__(256) void bsort_kernel(
    const unsigned int* __restrict__ pairs, const int* __restrict__ gscan,
    int* __restrict__ rowptr, int* __restrict__ col, int E, int N, int NB) {
  __shared__ int cnt[NPB];
  __shared__ int scn[NPB];
  __shared__ int cur[NPB];
  __shared__ int part[256];
  const int t = threadIdx.x, b = blockIdx.x;
  const int base = gscan[(size_t)b * NBLK_C];
  const int bend = (b + 1 < NB) ? gscan[(size_t)(b + 1) * NBLK_C] : E;
  const int n0 = b << NPB_SHIFT;

  cnt[2 * t] = 0; cnt[2 * t + 1] = 0;
  __syncthreads();
  for (int j = base + t; j < bend; j += 256)
    atomicAdd(&cnt[pairs[j] & (NPB - 1)], 1);
  __syncthreads();

  int c0 = cnt[2 * t], c1 = cnt[2 * t + 1];
  part[t] = c0 + c1;
  __syncthreads();
  for (int off = 1; off < 256; off <<= 1) {
    int u = (t >= off) ? part[t - off] : 0;
    __syncthreads();
    part[t] += u;
    __syncthreads();
  }
  int exc = part[t] - (c0 + c1);
  scn[2 * t] = exc; scn[2 * t + 1] = exc + c0;
  cur[2 * t] = base + exc; cur[2 * t + 1] = base + exc + c0;

  int g0 = n0 + 2 * t, g1 = n0 + 2 * t + 1;
  if (g0 < N) rowptr[g0] = base + scn[2 * t];
  if (g1 < N) rowptr[g1] = base + scn[2 * t + 1];
  if (b == NB - 1 && t == 0) rowptr[N] = E;
  __syncthreads();

  for (int j = base + t; j < bend; j += 256) {
    unsigned int p = pairs[j];
    int pos = atomicAdd(&cur[p & (NPB - 1)], 1);
    col[pos] = (int)((p >> NPB_SHIFT) << 7);   // byte offset
  }
}

// --- cast x (f32) -> xb (bf16), vectorized
__global__ __launch_bounds__(256) void castx_kernel(
    const float4* __restrict__ X, ushort4* __restrict__ XB, int tot4) {
  int i = blockIdx.x * 256 + threadIdx.x;
  if (i >= tot4) return;
  float4 v = X[i];
  ushort4 r;
  r.x = f2b(v.x); r.y = f2b(v.y); r.z = f2b(v.z); r.w = f2b(v.w);
  XB[i] = r;
}

// --- all 4 weight transposes in one launch. Wt[fo][k] = bf16(W[k][fo]),
// zero-padded. Segments: W1a(8192) W2a(16384) W1b(8192) W2b(3072) = 35840.
__global__ __launch_bounds__(256) void transw_all_kernel(
    const float* __restrict__ W1a, const float* __restrict__ W2a,
    const float* __restrict__ W1b, const float* __restrict__ W2b,
    unsigned short* __restrict__ Wt1, unsigned short* __restrict__ Wt2,
    unsigned short* __restrict__ Wt3, unsigned short* __restrict__ Wt4) {
  int i = blockIdx.x * 256 + threadIdx.x;
  const float* W; unsigned short* Wt; int Fi, FiPad, Fo;
  if (i < 8192)        { W = W1a; Wt = Wt1; Fi = 64;  FiPad = 64;  Fo = 128; }
  else if (i < 24576)  { i -= 8192;  W = W2a; Wt = Wt2; Fi = 128; FiPad = 128; Fo = 128; }
  else if (i < 32768)  { i -= 24576; W = W1b; Wt = Wt3; Fi = 128; FiPad = 128; Fo = 40; }
  else if (i < 35840)  { i -= 32768; W = W2b; Wt = Wt4; Fi = 40;  FiPad = 64;  Fo = 40; }
  else return;
  int fo = i / FiPad, k = i - fo * FiPad;
  float v = (fo < Fo && k < Fi) ? W[(size_t)k * Fo + fo] : 0.f;
  Wt[i] = f2b(v);
}

// --- gather over bf16 [N,64] rows: out[n] = bf16(X[n] + sum X[col[j]])
// One wave per node, lane = feature, byte-offset col[], 8-wide unroll.
__global__ __launch_bounds__(256) void gatherB_kernel(
    const unsigned short* __restrict__ X, const int* __restrict__ rowptr,
    const int* __restrict__ colb, unsigned short* __restrict__ out, int N) {
  const int lane = threadIdx.x & 63;
  const int n = blockIdx.x * 4 + (threadIdx.x >> 6);
  if (n >= N) return;
  const char* Xc = (const char*)X;
  const int l2 = lane * 2;
  const int beg = rowptr[n], end = rowptr[n + 1];
  float a0 = b2f(*(const unsigned short*)(Xc + ((size_t)n << 7) + l2));
  float a1 = 0.f, a2 = 0.f, a3 = 0.f;
  int j = beg;
  for (; j + 8 <= end; j += 8) {
    int c0 = colb[j],     c1 = colb[j + 1], c2 = colb[j + 2], c3 = colb[j + 3];
    int c4 = colb[j + 4], c5 = colb[j + 5], c6 = colb[j + 6], c7 = colb[j + 7];
    float v0 = b2f(*(const unsigned short*)(Xc + c0 + l2));
    float v1 = b2f(*(const unsigned short*)(Xc + c1 + l2));
    float v2 = b2f(*(const unsigned short*)(Xc + c2 + l2));
    float v3 = b2f(*(const unsigned short*)(Xc + c3 + l2));
    float v4 = b2f(*(const unsigned short*)(Xc + c4 + l2));
    float v5 = b2f(*(const unsigned short*)(Xc + c5 + l2));
    float v6 = b2f(*(const unsigned short*)(Xc + c6 + l2));
    float v7 = b2f(*(const unsigned short*)(Xc + c7 + l2));
    a0 += v0 + v4; a1 += v1 + v5; a2 += v2 + v6; a3 += v3 + v7;
  }
  for (; j + 4 <= end; j += 4) {
    int c0 = colb[j], c1 = colb[j + 1], c2 = colb[j + 2], c3 = colb[j + 3];
    a0 += b2f(*(const unsigned short*)(Xc + c0 + l2));
    a1 += b2f(*(const unsigned short*)(Xc + c1 + l2));
    a2 += b2f(*(const unsigned short*)(Xc + c2 + l2));
    a3 += b2f(*(const unsigned short*)(Xc + c3 + l2));
  }
  for (; j < end; ++j) a0 += b2f(*(const unsigned short*)(Xc + colb[j] + l2));
  out[(size_t)n * 64 + lane] = f2b(a0 + a1 + a2 + a3);
}

// --- fused 3-stage MLP: m = (relu(relu(xa@W1+b1)@W2+b2))@W3.
// mid and h share one swizzled LDS tile [64][128]; h never hits global.
// Block: 4 waves x 16 nodes. 80 KB LDS -> 2 blocks/CU.
__global__ __launch_bounds__(256) void gemm123_kernel(
    const unsigned short* __restrict__ A, const unsigned short* __restrict__ W1G,
    const unsigned short* __restrict__ W2G, const unsigned short* __restrict__ W3G,
    const float* __restrict__ b1, const float* __restrict__ b2,
    unsigned short* __restrict__ outM, int N) {
  __shared__ unsigned short W1l[128 * 64];    // 16 KB
  __shared__ unsigned short W2l[128 * 128];   // 32 KB
  __shared__ unsigned short W3l[64 * 128];    // 16 KB
  __shared__ unsigned short Ml[64 * 128];     // 16 KB (mid, then h)
  const int t = threadIdx.x;
  const int n0 = blockIdx.x * 64;

  for (int c = t; c < 128 * 64 / 8; c += 256) {      // W1: CPR=8
    int row = c >> 3;
    uint4 v = ((const uint4*)W1G)[c];
    int boff = (c * 16) ^ ((row & 7) << 4);
    *(uint4*)((char*)W1l + boff) = v;
  }
  for (int c = t; c < 128 * 128 / 8; c += 256) {     // W2: CPR=16
    int row = c >> 4;
    uint4 v = ((const uint4*)W2G)[c];
    int boff = (c * 16) ^ ((row & 7) << 4);
    *(uint4*)((char*)W2l + boff) = v;
  }
  for (int c = t; c < 64 * 128 / 8; c += 256) {      // W3: CPR=16
    int row = c >> 4;
    uint4 v = ((const uint4*)W3G)[c];
    int boff = (c * 16) ^ ((row & 7) << 4);
    *(uint4*)((char*)W3l + boff) = v;
  }
  __syncthreads();

  const int l = t & 63, w = t >> 6;
  const int kgrp = l >> 4, rc = l & 15;
  int arow = n0 + w * 16 + rc;
  int arowc = arow < N ? arow : N - 1;
  const int arow2 = w * 16 + rc;

  f32x4 acc[8];
#pragma unroll
  for (int nf = 0; nf < 8; ++nf) acc[nf] = (f32x4){0.f, 0.f, 0.f, 0.f};

  // stage 1: mid = relu(xa@W1 + b1)
#pragma unroll
  for (int k0 = 0; k0 < 64; k0 += 32) {
    bf16x8 a = *(const bf16x8*)(A + (size_t)arowc * 64 + k0 + kgrp * 8);
#pragma unroll
    for (int nf = 0; nf < 8; ++nf) {
      int frow = nf * 16 + rc;
      int boff = ((frow * 64 + k0 + kgrp * 8) * 2) ^ ((frow & 7) << 4);
      bf16x8 b = *(const bf16x8*)((const char*)W1l + boff);
      acc[nf] = __builtin_amdgcn_mfma_f32_16x16x32_bf16(a, b, acc[nf], 0, 0, 0);
    }
  }
#pragma unroll
  for (int nf = 0; nf < 8; ++nf) {
    int colv = nf * 16 + rc;
    float bs = b1[colv];
    int chunk = colv >> 3;
    int inb = (rc & 7) * 2;
#pragma unroll
    for (int q = 0; q < 4; ++q) {
      int row = w * 16 + kgrp * 4 + q;
      float v = fmaxf(acc[nf][q] + bs, 0.f);
      int boff = row * 256 + ((chunk * 16) ^ ((row & 7) << 4)) + inb;
      *(unsigned short*)((char*)Ml + boff) = f2b(v);
    }
  }
  __syncthreads();

  // stage 2: h = relu(mid@W2 + b2)   (held in acc, then written back to Ml)
#pragma unroll
  for (int nf = 0; nf < 8; ++nf) acc[nf] = (f32x4){0.f, 0.f, 0.f, 0.f};
#pragma unroll
  for (int k0 = 0; k0 < 128; k0 += 32) {
    int chunk = (k0 >> 3) + kgrp;
    int aoff = arow2 * 256 + ((chunk * 16) ^ ((arow2 & 7) << 4));
    bf16x8 a = *(const bf16x8*)((const char*)Ml + aoff);
#pragma unroll
    for (int nf = 0; nf < 8; ++nf) {
      int frow = nf * 16 + rc;
      int boff = ((frow * 128 + k0 + kgrp * 8) * 2) ^ ((frow & 7) << 4);
      bf16x8 b = *(const bf16x8*)((const char*)W2l + boff);
      acc[nf] = __builtin_amdgcn_mfma_f32_16x16x32_bf16(a, b, acc[nf], 0, 0, 0);
    }
  }
  __syncthreads();   // all waves done READING Ml(mid) before overwriting with h
#pragma unroll
  for (int nf = 0; nf < 8; ++nf) {
    int colv = nf * 16 + rc;
    float bs = b2[colv];
    int chunk = colv >> 3;
    int inb = (rc & 7) * 2;
#pragma unroll
    for (int q = 0; q < 4; ++q) {
      int row = w * 16 + kgrp * 4 + q;
      float v = fmaxf(acc[nf][q] + bs, 0.f);
      int boff = row * 256 + ((chunk * 16) ^ ((row & 7) << 4)) + inb;
      *(unsigned short*)((char*)Ml + boff) = f2b(v);
    }
  }
  __syncthreads();

  // stage 3: m = h@W3  (cols 40..63 zero via padded W3)
  f32x4 acc3[4];
#pragma unroll
  for (int nf = 0; nf < 4; ++nf) acc3[nf] = (f32x4){0.f, 0.f, 0.f, 0.f};
#pragma unroll
  for (int k0 = 0; k0 < 128; k0 += 32) {
    int chunk = (k0 >> 3) + kgrp;
    int aoff = arow2 * 256 + ((chunk * 16) ^ ((arow2 & 7) << 4));
    bf16x8 a = *(const bf16x8*)((const char*)Ml + aoff);
#pragma unroll
    for (int nf = 0; nf < 4; ++nf) {
      int frow = nf * 16 + rc;
      int boff = ((frow * 128 + k0 + kgrp * 8) * 2) ^ ((frow & 7) << 4);
      bf16x8 b = *(const bf16x8*)((const char*)W3l + boff);
      acc3[nf] = __builtin_amdgcn_mfma_f32_16x16x32_bf16(a, b, acc3[nf], 0, 0, 0);
    }
  }
#pragma unroll
  for (int nf = 0; nf < 4; ++nf) {
    int fo = nf * 16 + rc;
#pragma unroll
    for (int q = 0; q < 4; ++q) {
      int n = n0 + w * 16 + kgrp * 4 + q;
      if (n < N) outM[(size_t)n * 64 + fo] = f2b(acc3[nf][q]);
    }
  }
}

// --- fused final: per 64-node block, gather v=relu(m + Am + b1b) into a
// swizzled LDS tile, then z = v@W2b + b2b (MFMA, FoPad=48) + log_softmax.
__global__ __launch_bounds__(256) void gather_sm_kernel(
    const unsigned short* __restrict__ M, const int* __restrict__ rowptr,
    const int* __restrict__ colb, const float* __restrict__ b1,
    const unsigned short* __restrict__ W4G, const float* __restrict__ b2,
    float* __restrict__ out, int N) {
  __shared__ unsigned short Vl[64 * 64];    // 8 KB
  __shared__ unsigned short W4l[48 * 64];   // 6 KB
  __shared__ float bl[48];
  const int t = threadIdx.x;
  const int n0 = blockIdx.x * 64;

  for (int c = t; c < 48 * 64 / 8; c += 256) {   // CPR=8
    int row = c >> 3;
    uint4 v = ((const uint4*)W4G)[c];
    int boff = (c * 16) ^ ((row & 7) << 4);
    *(uint4*)((char*)W4l + boff) = v;
  }
  if (t < 48) bl[t] = (t < 40) ? b2[t] : 0.f;

  const int l = t & 63, w = t >> 6;
  const int l2 = l * 2;
  const char* Mc = (const char*)M;
  const float bb = (l < 40) ? b1[l] : 0.f;

  // phase A: each wave gathers 16 node rows (8-wide unrolled)
  for (int i = 0; i < 16; ++i) {
    const int row = w * 16 + i;
    const int n = n0 + row;
    float r = 0.f;
    if (n < N) {
      const int beg = rowptr[n], end = rowptr[n + 1];
      float a0 = b2f(*(const unsigned short*)(Mc + ((size_t)n << 7) + l2));
      float a1 = 0.f, a2 = 0.f, a3 = 0.f;
      int j = beg;
      for (; j + 8 <= end; j += 8) {
        int c0 = colb[j],     c1 = colb[j + 1], c2 = colb[j + 2], c3 = colb[j + 3];
        int c4 = colb[j + 4], c5 = colb[j + 5], c6 = colb[j + 6], c7 = colb[j + 7];
        float v0 = b2f(*(const unsigned short*)(Mc + c0 + l2));
        float v1 = b2f(*(const unsigned short*)(Mc + c1 + l2));
        float v2 = b2f(*(const unsigned short*)(Mc + c2 + l2));
        float v3 = b2f(*(const unsigned short*)(Mc + c3 + l2));
        float v4 = b2f(*(const unsigned short*)(Mc + c4 + l2));
        float v5 = b2f(*(const unsigned short*)(Mc + c5 + l2));
        float v6 = b2f(*(const unsigned short*)(Mc + c6 + l2));
        float v7 = b2f(*(const unsigned short*)(Mc + c7 + l2));
        a0 += v0 + v4; a1 += v1 + v5; a2 += v2 + v6; a3 += v3 + v7;
      }
      for (; j + 4 <= end; j += 4) {
        int c0 = colb[j], c1 = colb[j + 1], c2 = colb[j + 2], c3 = colb[j + 3];
        a0 += b2f(*(const unsigned short*)(Mc + c0 + l2));
        a1 += b2f(*(const unsigned short*)(Mc + c1 + l2));
        a2 += b2f(*(const unsigned short*)(Mc + c2 + l2));
        a3 += b2f(*(const unsigned short*)(Mc + c3 + l2));
      }
      for (; j < end; ++j) a0 += b2f(*(const unsigned short*)(Mc + colb[j] + l2));
      r = fmaxf(a0 + a1 + a2 + a3 + bb, 0.f);
      if (l >= 40) r = 0.f;   // padded features: force exact zero
    }
    int chunk = l >> 3;
    int boff = row * 128 + ((chunk * 16) ^ ((row & 7) << 4)) + (l & 7) * 2;
    *(unsigned short*)((char*)Vl + boff) = f2b(r);
  }
  __syncthreads();

  // phase B: z = V@W4 + b2, log_softmax, write f32 out
  const int kgrp = l >> 4, rc = l & 15;
  const int arow = w * 16 + rc;
  f32x4 acc[3];
#pragma unroll
  for (int nf = 0; nf < 3; ++nf) acc[nf] = (f32x4){0.f, 0.f, 0.f, 0.f};
#pragma unroll
  for (int k0 = 0; k0 < 64; k0 += 32) {
    int chunk = (k0 >> 3) + kgrp;
    int aoff = arow * 128 + ((chunk * 16) ^ ((arow & 7) << 4));
    bf16x8 a = *(const bf16x8*)((const char*)Vl + aoff);
#pragma unroll
    for (int nf = 0; nf < 3; ++nf) {
      int frow = nf * 16 + rc;
      int boff = ((frow * 64 + k0 + kgrp * 8) * 2) ^ ((frow & 7) << 4);
      bf16x8 b = *(const bf16x8*)((const char*)W4l + boff);
      acc[nf] = __builtin_amdgcn_mfma_f32_16x16x32_bf16(a, b, acc[nf], 0, 0, 0);
    }
  }

  const bool v2 = (rc < 8);
  float bs0 = bl[rc], bs1 = bl[16 + rc], bs2 = bl[32 + rc];
#pragma unroll
  for (int q = 0; q < 4; ++q) {
    float z0 = acc[0][q] + bs0;
    float z1 = acc[1][q] + bs1;
    float z2 = acc[2][q] + bs2;
    float m = fmaxf(z0, z1);
    if (v2) m = fmaxf(m, z2);
#pragma unroll
    for (int o = 8; o >= 1; o >>= 1) m = fmaxf(m, __shfl_xor(m, o, 64));
    float s = expf(z0 - m) + expf(z1 - m) + (v2 ? expf(z2 - m) : 0.f);
#pragma unroll
    for (int o = 8; o >= 1; o >>= 1) s += __shfl_xor(s, o, 64);
    float ls = m + logf(s);
    int n = n0 + w * 16 + kgrp * 4 + q;
    if (n < N) {
      float* op = out + (size_t)n * 40;
      op[rc] = z0 - ls;
      op[16 + rc] = z1 - ls;
      if (v2) op[32 + rc] = z2 - ls;
    }
  }
}

extern "C" void kernel_launch(void* const* d_in, const int* in_sizes, int n_in,
                              void* d_out, int out_size, void* d_ws, size_t ws_size,
                              hipStream_t stream) {
  const float*        x   = (const float*)d_in[0];
  const unsigned int* ew  = (const unsigned int*)d_in[1];
  const float*        W1a = (const float*)d_in[2];
  const float*        b1a = (const float*)d_in[3];
  const float*        W2a = (const float*)d_in[4];
  const float*        b2a = (const float*)d_in[5];
  const float*        W1b = (const float*)d_in[6];
  const float*        b1b = (const float*)d_in[7];
  const float*        W2b = (const float*)d_in[8];
  const float*        b2b = (const float*)d_in[9];

  const int N = in_sizes[0] / 64;     // 100000
  const int E = in_sizes[1] / 2;      // 1200000
  const int NB = (N + NPB - 1) >> NPB_SHIFT;   // coarse buckets (196)
  float* out = (float*)d_out;

  char* ws = (char*)d_ws;
  size_t off = 0;
  auto alloc = [&](size_t bytes) {
    char* p = ws + off;
    off += (bytes + WS_ALIGN - 1) & ~(size_t)(WS_ALIGN - 1);
    return p;
  };
  unsigned int*  flag   = (unsigned int*)alloc(4);
  int*           rowptr = (int*)alloc((size_t)(N + 2) * 4);
  int*           gscan  = (int*)alloc((size_t)NB * NBLK_C * 4);
  int*           bsum2  = (int*)alloc(256 * 4);
  int*           col    = (int*)alloc((size_t)E * 4);       // byte offsets
  unsigned short* Wt1   = (unsigned short*)alloc((size_t)128 * 64 * 2);
  unsigned short* Wt2   = (unsigned short*)alloc((size_t)128 * 128 * 2);
  unsigned short* Wt3   = (unsigned short*)alloc((size_t)64 * 128 * 2);
  unsigned short* Wt4   = (unsigned short*)alloc((size_t)48 * 64 * 2);
  unsigned short* xb    = (unsigned short*)alloc((size_t)N * 64 * 2);   // bf16 x
  unsigned short* xa    = (unsigned short*)alloc((size_t)N * 64 * 2);   // x+Ax
  unsigned short* m     = (unsigned short*)alloc((size_t)N * 64 * 2);   // h@W1b
  // CSR-build staging aliases (lifetimes end before xa/m are written):
  unsigned int*  pairs_u = (unsigned int*)xa;                       // 4.8 MB
  unsigned char* bucket8 = (unsigned char*)(xa + (size_t)N * 38);   // 1.2 MB (within xa)
  unsigned int*  pairs_s = (unsigned int*)m;                        // 4.8 MB

  hipMemsetAsync(flag, 0, 4, stream);
  sniff_kernel<<<1, 256, 0, stream>>>(ew, flag, E);

  // --- CSR build
  const size_t ldsNB = (size_t)NB * 4;
  const int tot = NB * NBLK_C;
  const int nb2 = (tot + SCAN_E - 1) / SCAN_E;
  ehist_kernel<<<NBLK_C, 256, ldsNB, stream>>>(ew, flag, gscan, pairs_u, bucket8, E, NB);
  pscan1_kernel<<<nb2, SCAN_T, 0, stream>>>(gscan, bsum2, tot);
  pscan2_kernel<<<1, 64, 0, stream>>>(bsum2, nb2);
  pscan3_kernel<<<nb2, SCAN_T, 0, stream>>>(gscan, bsum2, tot);
  bscatter2_kernel<<<NBLK_C, 256, ldsNB, stream>>>(pairs_u, bucket8, gscan, pairs_s, E, NB);
  bsort_kernel<<<NB, 256, 0, stream>>>(pairs_s, gscan, rowptr, col, E, N, NB);

  // casts / weight transposes (bf16)
  castx_kernel<<<(N * 16 + 255) / 256, 256, 0, stream>>>((const float4*)x, (ushort4*)xb, N * 16);
  transw_all_kernel<<<140, 256, 0, stream>>>(W1a, W2a, W1b, W2b, Wt1, Wt2, Wt3, Wt4);

  const int gGather = (N + 3) / 4;
  const int gGemm = (N + 63) / 64;

  // conv1 + conv2 projection: xa = x + A x ; m = relu(relu(xa@W1a+b1a)@W2a+b2a)@W1b
  gatherB_kernel<<<gGather, 256, 0, stream>>>(xb, rowptr, col, xa, N);
  gemm123_kernel<<<gGemm, 256, 0, stream>>>(xa, Wt1, Wt2, Wt3, b1a, b2a, m, N);

  // out = lsm(relu(m + Am + b1b)@W2b + b2b)  (fused gather+GEMM+softmax)
  gather_sm_kernel<<<gGemm, 256, 0, stream>>>(m, rowptr, col, b1b, Wt4, b2b, out, N);
}